// Round 1
// baseline (373.196 us; speedup 1.0000x reference)
//
#include <hip/hip_runtime.h>
#include <hip/hip_bf16.h>
#include <cstdint>
#include <cstddef>

typedef __bf16 bf16;
typedef __attribute__((ext_vector_type(8))) __bf16 bf16x8;
typedef __attribute__((ext_vector_type(4))) __bf16 bf16x4v;
typedef __attribute__((ext_vector_type(4))) float f32x4;

#define NB 2
#define NT 2048
#define NE 2048
#define NH 32
#define NHKV 8
#define ND 64
#define NBT (NB * NT)
#define NQKV 3072

__device__ __forceinline__ void gload_lds16(const void* g, void* l) {
  __builtin_amdgcn_global_load_lds(
      (const __attribute__((address_space(1))) unsigned int*)g,
      (__attribute__((address_space(3))) unsigned int*)l, 16, 0, 0);
}

// XOR swizzle for 128-byte LDS rows: spreads the 16-way bank conflict.
__device__ __forceinline__ int swz(int row, int byteoff) {
  return (row * 128 + byteoff) ^ ((row & 7) << 4);
}

// ---------------------------------------------------------------- pack kernels

__global__ void cvt_bf16_kernel(const float* __restrict__ in, bf16* __restrict__ out, int n4) {
  int i = blockIdx.x * blockDim.x + threadIdx.x;
  const int stride = gridDim.x * blockDim.x;
  for (; i < n4; i += stride) {
    const float4 v = ((const float4*)in)[i];
    bf16x4v o;
    o[0] = (bf16)v.x; o[1] = (bf16)v.y; o[2] = (bf16)v.z; o[3] = (bf16)v.w;
    ((bf16x4v*)out)[i] = o;
  }
}

// out[rowoff + c][k] = (bf16) in[k][c];  in: [2048][ncols] fp32, out LD = 2048
__global__ void transpose_cvt_kernel(const float* __restrict__ in, bf16* __restrict__ out,
                                     int ncols, int rowoff) {
  __shared__ float tile[32][33];
  const int c0 = blockIdx.x * 32;
  const int k0 = blockIdx.y * 32;
  const int tx = threadIdx.x, ty = threadIdx.y;
#pragma unroll
  for (int j = 0; j < 4; ++j)
    tile[ty + j * 8][tx] = in[(size_t)(k0 + ty + j * 8) * ncols + c0 + tx];
  __syncthreads();
#pragma unroll
  for (int j = 0; j < 4; ++j)
    out[(size_t)(rowoff + c0 + ty + j * 8) * 2048 + k0 + tx] = (bf16)tile[tx][ty + j * 8];
}

__global__ void rope_table_kernel(float* __restrict__ tab) {
  int i = blockIdx.x * 256 + threadIdx.x;
  if (i >= NT * 32) return;
  const int t = i >> 5, d = i & 31;
  const float inv = expf(-(float)d * 0.28782313662425574f);  // ln(10000)/32
  const float ang = (float)t * inv;
  tab[t * 64 + d] = cosf(ang);
  tab[t * 64 + 32 + d] = sinf(ang);
}

__global__ void rope_apply_kernel(bf16* __restrict__ qkv, const float* __restrict__ tab) {
  const int PP = NH * 32 + NHKV * 32;  // 1280 rotation pairs per token row
  int i = blockIdx.x * 256 + threadIdx.x;
  if (i >= NBT * PP) return;
  const int row = i / PP, r = i % PP;
  const int t = row & (NT - 1);
  int col, d;
  if (r < 1024) { d = r & 31; col = (r >> 5) * 64 + d; }
  else { const int rr = r - 1024; d = rr & 31; col = 2048 + (rr >> 5) * 64 + d; }
  const float c = tab[t * 64 + d], s = tab[t * 64 + 32 + d];
  const size_t base = (size_t)row * NQKV;
  const float x1 = (float)qkv[base + col];
  const float x2 = (float)qkv[base + col + 32];
  qkv[base + col] = (bf16)(x1 * c - x2 * s);
  qkv[base + col + 32] = (bf16)(x2 * c + x1 * s);
}

// vt[b][hk][d][t] = qkv[b*T+t][2560 + hk*64 + d]
__global__ void build_vt_kernel(const bf16* __restrict__ qkv, bf16* __restrict__ vt) {
  __shared__ bf16 tile[32][33];
  const int bhk = blockIdx.z;
  const int b = bhk >> 3, hk = bhk & 7;
  const int d0 = blockIdx.x * 32, t0 = blockIdx.y * 32;
  const int tx = threadIdx.x, ty = threadIdx.y;
#pragma unroll
  for (int j = 0; j < 4; ++j)
    tile[ty + j * 8][tx] = qkv[(size_t)(b * NT + t0 + ty + j * 8) * NQKV + 2560 + hk * 64 + d0 + tx];
  __syncthreads();
#pragma unroll
  for (int j = 0; j < 4; ++j)
    vt[((size_t)(b * NHKV + hk) * 64 + d0 + ty + j * 8) * NT + t0 + tx] = tile[tx][ty + j * 8];
}

// ---------------------------------------------------------------- GEMM (B^T)
// C[M][N] = A[M][K] * Bt[N][K]^T ; 128x128 tile, BK=32, 4 waves

template <typename CT>
__global__ __launch_bounds__(256)
void gemm_bt_kernel(const bf16* __restrict__ A, const bf16* __restrict__ Bt,
                    CT* __restrict__ C, int M, int N, int K) {
  __shared__ __align__(16) bf16 As[128 * 32];
  __shared__ __align__(16) bf16 Bs[128 * 32];
  const int tid = threadIdx.x;
  const int lane = tid & 63, wid = tid >> 6;
  const int wr = wid >> 1, wc = wid & 1;
  const int m0 = blockIdx.y * 128, n0 = blockIdx.x * 128;
  const int srow = tid >> 2;          // 0..63 staging row
  const int skoff = (tid & 3) * 8;    // staging k offset
  const bf16* ga = A + (size_t)(m0 + srow) * K + skoff;
  const bf16* gb = Bt + (size_t)(n0 + srow) * K + skoff;
  const int fr = lane & 15;
  const int fk = (lane >> 4) * 8;
  f32x4 acc[4][4] = {};

  for (int k0 = 0; k0 < K; k0 += 32) {
    gload_lds16(ga + k0, &As[tid * 8]);
    gload_lds16(ga + k0 + (size_t)64 * K, &As[2048 + tid * 8]);
    gload_lds16(gb + k0, &Bs[tid * 8]);
    gload_lds16(gb + k0 + (size_t)64 * K, &Bs[2048 + tid * 8]);
    __syncthreads();
    bf16x8 af[4], bfr[4];
#pragma unroll
    for (int m = 0; m < 4; ++m)
      af[m] = *(const bf16x8*)&As[(wr * 64 + m * 16 + fr) * 32 + fk];
#pragma unroll
    for (int n = 0; n < 4; ++n)
      bfr[n] = *(const bf16x8*)&Bs[(wc * 64 + n * 16 + fr) * 32 + fk];
#pragma unroll
    for (int m = 0; m < 4; ++m)
#pragma unroll
      for (int n = 0; n < 4; ++n)
        acc[m][n] = __builtin_amdgcn_mfma_f32_16x16x32_bf16(af[m], bfr[n], acc[m][n], 0, 0, 0);
    __syncthreads();
  }

  const int orow0 = m0 + wr * 64 + (lane >> 4) * 4;
  const int ocol0 = n0 + wc * 64 + fr;
#pragma unroll
  for (int m = 0; m < 4; ++m)
#pragma unroll
    for (int n = 0; n < 4; ++n)
#pragma unroll
      for (int j = 0; j < 4; ++j)
        C[(size_t)(orow0 + m * 16 + j) * N + ocol0 + n * 16] = (CT)acc[m][n][j];
}

// ---------------------------------------------------------------- attention
// One block = 64 q rows of one (b,h). 4 waves x 16 rows. KBLK = 64, causal.

__global__ __launch_bounds__(256)
void attn_kernel(const bf16* __restrict__ qkv, const bf16* __restrict__ vt,
                 bf16* __restrict__ y) {
  const int qt = blockIdx.x;
  const int bh = blockIdx.y;
  const int b = bh >> 5, h = bh & 31, hk = h >> 2;
  const int q0 = qt * 64;
  __shared__ __align__(16) bf16 Ks[64 * 64];
  __shared__ __align__(16) bf16 Vs[64 * 64];   // V^T tile: row=d, col=kv
  __shared__ __align__(16) bf16 Ps[4 * 16 * 64];
  const int tid = threadIdx.x;
  const int lane = tid & 63, wid = tid >> 6;
  const int fr = lane & 15;
  const int fk = (lane >> 4) * 8;
  const int jr = (lane >> 4) * 4;

  bf16x8 aq0, aq1;
  {
    const bf16* qp = qkv + (size_t)(b * NT + q0 + wid * 16 + fr) * NQKV + h * 64 + fk;
    aq0 = *(const bf16x8*)qp;
    aq1 = *(const bf16x8*)(qp + 32);
  }
  float m_s[4] = {-1e30f, -1e30f, -1e30f, -1e30f};
  float l_s[4] = {0.f, 0.f, 0.f, 0.f};
  f32x4 o[4] = {};

  const int st_r = tid >> 3;
  const int st_c = (tid & 7) * 8;
  const bf16* kg_base = qkv + (size_t)(b * NT + st_r) * NQKV + 2048 + hk * 64 + st_c;
  const bf16* vg_base = vt + ((size_t)(b * NHKV + hk) * 64 + st_r) * NT + st_c;
  bf16* pw = Ps + wid * 1024;

  const int ntiles = qt + 1;
  for (int it = 0; it < ntiles; ++it) {
    const int kv0 = it * 64;
    {
      const bf16* kg = kg_base + (size_t)kv0 * NQKV;
      bf16x8 ka = *(const bf16x8*)kg;
      bf16x8 kb = *(const bf16x8*)(kg + (size_t)32 * NQKV);
      const bf16* vg = vg_base + kv0;
      bf16x8 va = *(const bf16x8*)vg;
      bf16x8 vb = *(const bf16x8*)(vg + 32 * NT);
      *(bf16x8*)((char*)Ks + swz(st_r, st_c * 2)) = ka;
      *(bf16x8*)((char*)Ks + swz(st_r + 32, st_c * 2)) = kb;
      *(bf16x8*)((char*)Vs + swz(st_r, st_c * 2)) = va;
      *(bf16x8*)((char*)Vs + swz(st_r + 32, st_c * 2)) = vb;
    }
    __syncthreads();

    // S = Q K^T for this wave's 16 q rows x 64 kv cols
    f32x4 s[4] = {};
#pragma unroll
    for (int n = 0; n < 4; ++n) {
      bf16x8 bk0 = *(const bf16x8*)((const char*)Ks + swz(n * 16 + fr, fk * 2));
      bf16x8 bk1 = *(const bf16x8*)((const char*)Ks + swz(n * 16 + fr, 64 + fk * 2));
      s[n] = __builtin_amdgcn_mfma_f32_16x16x32_bf16(aq0, bk0, s[n], 0, 0, 0);
      s[n] = __builtin_amdgcn_mfma_f32_16x16x32_bf16(aq1, bk1, s[n], 0, 0, 0);
    }

    float p[4][4];
    const int qlo = q0 + wid * 16;
    const bool need_mask = (kv0 + 63) > qlo;
#pragma unroll
    for (int n = 0; n < 4; ++n)
#pragma unroll
      for (int j = 0; j < 4; ++j) {
        float v = s[n][j] * 0.125f;
        if (need_mask && (kv0 + n * 16 + fr) > (qlo + jr + j)) v = -1e30f;
        p[n][j] = v;
      }

    // online softmax; row r data lives in the 16 lanes sharing lane>>4
#pragma unroll
    for (int j = 0; j < 4; ++j) {
      float rmax = fmaxf(fmaxf(p[0][j], p[1][j]), fmaxf(p[2][j], p[3][j]));
      rmax = fmaxf(rmax, __shfl_xor(rmax, 1));
      rmax = fmaxf(rmax, __shfl_xor(rmax, 2));
      rmax = fmaxf(rmax, __shfl_xor(rmax, 4));
      rmax = fmaxf(rmax, __shfl_xor(rmax, 8));
      const float mnew = fmaxf(m_s[j], rmax);
      const float sc = __expf(m_s[j] - mnew);
      m_s[j] = mnew;
      float rsum = 0.f;
#pragma unroll
      for (int n = 0; n < 4; ++n) {
        p[n][j] = __expf(p[n][j] - mnew);
        rsum += p[n][j];
      }
      rsum += __shfl_xor(rsum, 1);
      rsum += __shfl_xor(rsum, 2);
      rsum += __shfl_xor(rsum, 4);
      rsum += __shfl_xor(rsum, 8);
      l_s[j] = l_s[j] * sc + rsum;
      o[0][j] *= sc; o[1][j] *= sc; o[2][j] *= sc; o[3][j] *= sc;
    }

    // P -> LDS (per-wave region, swizzled) for the PV A-operand
#pragma unroll
    for (int n = 0; n < 4; ++n)
#pragma unroll
      for (int j = 0; j < 4; ++j)
        *(bf16*)((char*)pw + swz(jr + j, (n * 16 + fr) * 2)) = (bf16)p[n][j];
    __syncthreads();

    // O += P V
#pragma unroll
    for (int kc = 0; kc < 2; ++kc) {
      bf16x8 ap = *(const bf16x8*)((const char*)pw + swz(fr, kc * 64 + fk * 2));
#pragma unroll
      for (int n = 0; n < 4; ++n) {
        bf16x8 bv = *(const bf16x8*)((const char*)Vs + swz(n * 16 + fr, kc * 64 + fk * 2));
        o[n] = __builtin_amdgcn_mfma_f32_16x16x32_bf16(ap, bv, o[n], 0, 0, 0);
      }
    }
    __syncthreads();
  }

#pragma unroll
  for (int j = 0; j < 4; ++j) {
    const float inv = 1.0f / l_s[j];
    const size_t base = (size_t)(b * NT + q0 + wid * 16 + jr + j) * NE + h * 64;
#pragma unroll
    for (int n = 0; n < 4; ++n)
      y[base + n * 16 + fr] = (bf16)(o[n][j] * inv);
  }
}

// ---------------------------------------------------------------- launch

extern "C" void kernel_launch(void* const* d_in, const int* in_sizes, int n_in,
                              void* d_out, int out_size, void* d_ws, size_t ws_size,
                              hipStream_t stream) {
  const float* x = (const float*)d_in[0];
  const float* Wq = (const float*)d_in[1];
  const float* Wk = (const float*)d_in[2];
  const float* Wv = (const float*)d_in[3];
  const float* Wo = (const float*)d_in[4];
  float* out = (float*)d_out;

  char* ws = (char*)d_ws;
  size_t off = 0;
  auto alloc = [&](size_t bytes) -> void* {
    void* p = ws + off;
    off += (bytes + 255) & ~(size_t)255;
    return p;
  };
  bf16* xb = (bf16*)alloc((size_t)NBT * NE * 2);
  bf16* wqkv_t = (bf16*)alloc((size_t)NQKV * NE * 2);
  bf16* wo_t = (bf16*)alloc((size_t)NE * NE * 2);
  bf16* qkv = (bf16*)alloc((size_t)NBT * NQKV * 2);
  bf16* vtb = (bf16*)alloc((size_t)NB * NHKV * ND * NT * 2);
  bf16* yb = (bf16*)alloc((size_t)NBT * NE * 2);
  float* tab = (float*)alloc((size_t)NT * 64 * 4);

  cvt_bf16_kernel<<<2048, 256, 0, stream>>>(x, xb, NBT * NE / 4);
  dim3 tb(32, 8);
  transpose_cvt_kernel<<<dim3(64, 64), tb, 0, stream>>>(Wq, wqkv_t, 2048, 0);
  transpose_cvt_kernel<<<dim3(16, 64), tb, 0, stream>>>(Wk, wqkv_t, 512, 2048);
  transpose_cvt_kernel<<<dim3(16, 64), tb, 0, stream>>>(Wv, wqkv_t, 512, 2560);
  transpose_cvt_kernel<<<dim3(64, 64), tb, 0, stream>>>(Wo, wo_t, 2048, 0);
  rope_table_kernel<<<(NT * 32 + 255) / 256, 256, 0, stream>>>(tab);

  gemm_bt_kernel<bf16><<<dim3(NQKV / 128, NBT / 128), 256, 0, stream>>>(
      xb, wqkv_t, qkv, NBT, NQKV, NE);
  rope_apply_kernel<<<(NBT * 1280 + 255) / 256, 256, 0, stream>>>(qkv, tab);
  build_vt_kernel<<<dim3(2, 64, 16), tb, 0, stream>>>(qkv, vtb);
  attn_kernel<<<dim3(NT / 64, NB * NH), 256, 0, stream>>>(qkv, vtb, yb);
  gemm_bt_kernel<float><<<dim3(NE / 128, NBT / 128), 256, 0, stream>>>(
      yb, wo_t, out, NBT, NE, NE);
}

// Round 2
// 304.741 us; speedup vs baseline: 1.2246x; 1.2246x over previous
//
#include <hip/hip_runtime.h>
#include <hip/hip_bf16.h>
#include <cstdint>
#include <cstddef>

typedef __bf16 bf16;
typedef __attribute__((ext_vector_type(8))) __bf16 bf16x8;
typedef __attribute__((ext_vector_type(4))) __bf16 bf16x4v;
typedef __attribute__((ext_vector_type(4))) float f32x4;

#define NB 2
#define NT 2048
#define NE 2048
#define NH 32
#define NHKV 8
#define ND 64
#define NBT (NB * NT)
#define NQKV 3072

__device__ __forceinline__ void gload_lds16(const void* g, void* l) {
  __builtin_amdgcn_global_load_lds(
      (const __attribute__((address_space(1))) unsigned int*)g,
      (__attribute__((address_space(3))) unsigned int*)l, 16, 0, 0);
}

// XOR swizzle for 128-byte LDS rows: spreads the 16-way bank conflict.
__device__ __forceinline__ int swz(int row, int byteoff) {
  return (row * 128 + byteoff) ^ ((row & 7) << 4);
}

// ---------------------------------------------------------------- pack kernels

__global__ void cvt_bf16_kernel(const float* __restrict__ in, bf16* __restrict__ out, int n4) {
  int i = blockIdx.x * blockDim.x + threadIdx.x;
  const int stride = gridDim.x * blockDim.x;
  for (; i < n4; i += stride) {
    const float4 v = ((const float4*)in)[i];
    bf16x4v o;
    o[0] = (bf16)v.x; o[1] = (bf16)v.y; o[2] = (bf16)v.z; o[3] = (bf16)v.w;
    ((bf16x4v*)out)[i] = o;
  }
}

// out[rowoff + c][k] = (bf16) in[k][c];  in: [2048][ncols] fp32, out LD = 2048
__global__ void transpose_cvt_kernel(const float* __restrict__ in, bf16* __restrict__ out,
                                     int ncols, int rowoff) {
  __shared__ float tile[32][33];
  const int c0 = blockIdx.x * 32;
  const int k0 = blockIdx.y * 32;
  const int tx = threadIdx.x, ty = threadIdx.y;
#pragma unroll
  for (int j = 0; j < 4; ++j)
    tile[ty + j * 8][tx] = in[(size_t)(k0 + ty + j * 8) * ncols + c0 + tx];
  __syncthreads();
#pragma unroll
  for (int j = 0; j < 4; ++j)
    out[(size_t)(rowoff + c0 + ty + j * 8) * 2048 + k0 + tx] = (bf16)tile[tx][ty + j * 8];
}

__global__ void rope_table_kernel(float* __restrict__ tab) {
  int i = blockIdx.x * 256 + threadIdx.x;
  if (i >= NT * 32) return;
  const int t = i >> 5, d = i & 31;
  const float inv = expf(-(float)d * 0.28782313662425574f);  // ln(10000)/32
  const float ang = (float)t * inv;
  tab[t * 64 + d] = cosf(ang);
  tab[t * 64 + 32 + d] = sinf(ang);
}

__global__ void rope_apply_kernel(bf16* __restrict__ qkv, const float* __restrict__ tab) {
  const int PP = NH * 32 + NHKV * 32;  // 1280 rotation pairs per token row
  int i = blockIdx.x * 256 + threadIdx.x;
  if (i >= NBT * PP) return;
  const int row = i / PP, r = i % PP;
  const int t = row & (NT - 1);
  int col, d;
  if (r < 1024) { d = r & 31; col = (r >> 5) * 64 + d; }
  else { const int rr = r - 1024; d = rr & 31; col = 2048 + (rr >> 5) * 64 + d; }
  const float c = tab[t * 64 + d], s = tab[t * 64 + 32 + d];
  const size_t base = (size_t)row * NQKV;
  const float x1 = (float)qkv[base + col];
  const float x2 = (float)qkv[base + col + 32];
  qkv[base + col] = (bf16)(x1 * c - x2 * s);
  qkv[base + col + 32] = (bf16)(x2 * c + x1 * s);
}

// vt[b][hk][d][t] = qkv[b*T+t][2560 + hk*64 + d]
__global__ void build_vt_kernel(const bf16* __restrict__ qkv, bf16* __restrict__ vt) {
  __shared__ bf16 tile[32][33];
  const int bhk = blockIdx.z;
  const int b = bhk >> 3, hk = bhk & 7;
  const int d0 = blockIdx.x * 32, t0 = blockIdx.y * 32;
  const int tx = threadIdx.x, ty = threadIdx.y;
#pragma unroll
  for (int j = 0; j < 4; ++j)
    tile[ty + j * 8][tx] = qkv[(size_t)(b * NT + t0 + ty + j * 8) * NQKV + 2560 + hk * 64 + d0 + tx];
  __syncthreads();
#pragma unroll
  for (int j = 0; j < 4; ++j)
    vt[((size_t)(b * NHKV + hk) * 64 + d0 + ty + j * 8) * NT + t0 + tx] = tile[tx][ty + j * 8];
}

// ---------------------------------------------------------------- GEMM (B^T)
// C[M][N] = A[M][K] * Bt[N][K]^T ; 128x128 tile, BK=32, 4 waves

template <typename CT>
__global__ __launch_bounds__(256)
void gemm_bt_kernel(const bf16* __restrict__ A, const bf16* __restrict__ Bt,
                    CT* __restrict__ C, int M, int N, int K) {
  __shared__ __align__(16) bf16 As[128 * 32];
  __shared__ __align__(16) bf16 Bs[128 * 32];
  const int tid = threadIdx.x;
  const int lane = tid & 63, wid = tid >> 6;
  const int wr = wid >> 1, wc = wid & 1;
  const int m0 = blockIdx.y * 128, n0 = blockIdx.x * 128;
  const int srow = tid >> 2;          // 0..63 staging row
  const int skoff = (tid & 3) * 8;    // staging k offset
  const bf16* ga = A + (size_t)(m0 + srow) * K + skoff;
  const bf16* gb = Bt + (size_t)(n0 + srow) * K + skoff;
  const int fr = lane & 15;
  const int fk = (lane >> 4) * 8;
  f32x4 acc[4][4] = {};

  for (int k0 = 0; k0 < K; k0 += 32) {
    gload_lds16(ga + k0, &As[tid * 8]);
    gload_lds16(ga + k0 + (size_t)64 * K, &As[2048 + tid * 8]);
    gload_lds16(gb + k0, &Bs[tid * 8]);
    gload_lds16(gb + k0 + (size_t)64 * K, &Bs[2048 + tid * 8]);
    __syncthreads();
    bf16x8 af[4], bfr[4];
#pragma unroll
    for (int m = 0; m < 4; ++m)
      af[m] = *(const bf16x8*)&As[(wr * 64 + m * 16 + fr) * 32 + fk];
#pragma unroll
    for (int n = 0; n < 4; ++n)
      bfr[n] = *(const bf16x8*)&Bs[(wc * 64 + n * 16 + fr) * 32 + fk];
#pragma unroll
    for (int m = 0; m < 4; ++m)
#pragma unroll
      for (int n = 0; n < 4; ++n)
        acc[m][n] = __builtin_amdgcn_mfma_f32_16x16x32_bf16(af[m], bfr[n], acc[m][n], 0, 0, 0);
    __syncthreads();
  }

  const int orow0 = m0 + wr * 64 + (lane >> 4) * 4;
  const int ocol0 = n0 + wc * 64 + fr;
#pragma unroll
  for (int m = 0; m < 4; ++m)
#pragma unroll
    for (int n = 0; n < 4; ++n)
#pragma unroll
      for (int j = 0; j < 4; ++j)
        C[(size_t)(orow0 + m * 16 + j) * N + ocol0 + n * 16] = (CT)acc[m][n][j];
}

// ---------------------------------------------------------------- attention
// Swapped-operand flash attention. One block = 128 q rows of one (b,h).
// 4 waves x 32 q rows (2 sets of 16). KVBLK = 64, causal.
// S^T = mfma(K_frag, Q_frag): lane holds S^T[kv][q=lane&15]; softmax fully
// in-register (15 fmax + 2 shfl_xor); kv row-permutation of the K fragment
// makes P concatenate directly into the PV x32 B-fragment (no LDS, no shfl).

__global__ __launch_bounds__(256)
void attn_kernel(const bf16* __restrict__ qkv, const bf16* __restrict__ vt,
                 bf16* __restrict__ y) {
  const int qtb = (int)gridDim.x - 1 - (int)blockIdx.x;  // big blocks first
  const int bh = blockIdx.y;
  const int b = bh >> 5, h = bh & 31, hk = h >> 2;
  const int q0 = qtb * 128;

  __shared__ __align__(16) bf16 Kb0[4096], Kb1[4096], Vb0[4096], Vb1[4096];

  const int tid = threadIdx.x;
  const int lane = tid & 63, wid = tid >> 6;
  const int ql = lane & 15;
  const int sub = lane >> 4;

  // staging: dest linear (row r=tid>>3, chunk c=tid&7); source chunk c^(r&7)
  const int st_r = tid >> 3;
  const int csw = ((tid & 7) ^ (st_r & 7)) * 8;
  const bf16* kgbase = qkv + (size_t)(b * NT + st_r) * NQKV + 2048 + hk * 64 + csw;
  const bf16* vgbase = vt + ((size_t)(b * NHKV + hk) * 64 + st_r) * NT + csw;

  auto STAGE = [&](bf16* Kd, bf16* Vd, int kv0) {
    const bf16* kg = kgbase + (size_t)kv0 * NQKV;
    gload_lds16(kg, Kd + tid * 8);
    gload_lds16(kg + (size_t)32 * NQKV, Kd + 2048 + tid * 8);
    const bf16* vg = vgbase + kv0;
    gload_lds16(vg, Vd + tid * 8);
    gload_lds16(vg + 32 * NT, Vd + 2048 + tid * 8);
  };

  // Q fragments (post-RoPE): B-operand, col=q=ql, k=d=sub*8+j (+32c)
  bf16x8 qf[2][2];
#pragma unroll
  for (int set = 0; set < 2; ++set) {
    const bf16* qp = qkv + (size_t)(b * NT + q0 + wid * 32 + set * 16 + ql) * NQKV + h * 64 + sub * 8;
    qf[set][0] = *(const bf16x8*)qp;
    qf[set][1] = *(const bf16x8*)(qp + 32);
  }

  f32x4 o[2][4] = {};
  float m_s[2] = {-1e30f, -1e30f};
  float l_s[2] = {0.f, 0.f};

  const int ntiles = 2 * qtb + 2;
  STAGE(Kb0, Vb0, 0);
  __syncthreads();

  int cur = 0;
  for (int it = 0; it < ntiles; ++it) {
    const int kv0 = it * 64;
    bf16* Ksb = cur ? Kb1 : Kb0;
    bf16* Vsb = cur ? Vb1 : Vb0;
    if (it + 1 < ntiles) STAGE(cur ? Kb0 : Kb1, cur ? Vb0 : Vb1, kv0 + 64);

    if (kv0 <= q0 + wid * 32 + 47) {  // at least one set active for this wave
      // K fragments with kv-permuted rows: abstract row r holds kv = kvmap(n,r)
      bf16x8 kf[4][2];
#pragma unroll
      for (int n = 0; n < 4; ++n) {
        const int kvr = 32 * (n >> 1) + 4 * (n & 1) + 8 * (ql >> 2) + (ql & 3);
#pragma unroll
        for (int c = 0; c < 2; ++c)
          kf[n][c] = *(const bf16x8*)((const char*)Ksb + swz(kvr, c * 64 + sub * 16));
      }
      // V^T fragments: A-operand, row=d=dt*16+ql, k=kv=kc*32+sub*8+j
      bf16x8 vf[2][4];
#pragma unroll
      for (int kc = 0; kc < 2; ++kc)
#pragma unroll
        for (int dt = 0; dt < 4; ++dt)
          vf[kc][dt] = *(const bf16x8*)((const char*)Vsb + swz(dt * 16 + ql, kc * 64 + sub * 16));

#pragma unroll
      for (int set = 0; set < 2; ++set) {
        const int qlo = q0 + wid * 32 + set * 16;
        if (kv0 > qlo + 15) continue;  // fully masked for this set

        f32x4 s[4] = {};
#pragma unroll
        for (int n = 0; n < 4; ++n) {
          s[n] = __builtin_amdgcn_mfma_f32_16x16x32_bf16(kf[n][0], qf[set][0], s[n], 0, 0, 0);
          s[n] = __builtin_amdgcn_mfma_f32_16x16x32_bf16(kf[n][1], qf[set][1], s[n], 0, 0, 0);
        }

        // lane holds S^T[kv = kv0+32(n>>1)+4(n&1)+8sub+j][q = qlo+ql]
        float p[4][4];
        if (kv0 + 63 > qlo) {
          const int qrow = qlo + ql;
#pragma unroll
          for (int n = 0; n < 4; ++n) {
            const int kvb = kv0 + 32 * (n >> 1) + 4 * (n & 1) + 8 * sub;
#pragma unroll
            for (int j = 0; j < 4; ++j) {
              float v = s[n][j] * 0.125f;
              if (kvb + j > qrow) v = -1e30f;
              p[n][j] = v;
            }
          }
        } else {
#pragma unroll
          for (int n = 0; n < 4; ++n)
#pragma unroll
            for (int j = 0; j < 4; ++j)
              p[n][j] = s[n][j] * 0.125f;
        }

        // in-register online softmax (column q lives in lanes ql+{0,16,32,48})
        float rmax = p[0][0];
#pragma unroll
        for (int n = 0; n < 4; ++n)
#pragma unroll
          for (int j = 0; j < 4; ++j) rmax = fmaxf(rmax, p[n][j]);
        rmax = fmaxf(rmax, __shfl_xor(rmax, 16));
        rmax = fmaxf(rmax, __shfl_xor(rmax, 32));
        const float mnew = fmaxf(m_s[set], rmax);
        const float sc = __expf(m_s[set] - mnew);
        m_s[set] = mnew;

        float rsum = 0.f;
        bf16x8 pb[2];  // [kc]: elements 0-3 from tile 2kc, 4-7 from tile 2kc+1
#pragma unroll
        for (int n = 0; n < 4; ++n)
#pragma unroll
          for (int j = 0; j < 4; ++j) {
            const float e = __expf(p[n][j] - mnew);
            rsum += e;
            pb[n >> 1][(n & 1) * 4 + j] = (bf16)e;
          }
        rsum += __shfl_xor(rsum, 16);
        rsum += __shfl_xor(rsum, 32);
        l_s[set] = l_s[set] * sc + rsum;
#pragma unroll
        for (int dt = 0; dt < 4; ++dt) o[set][dt] *= sc;

        // O^T[d][q] += V^T[d][kv] * P^T[kv][q]  (full-rate x32, P in-register)
#pragma unroll
        for (int kc = 0; kc < 2; ++kc)
#pragma unroll
          for (int dt = 0; dt < 4; ++dt)
            o[set][dt] = __builtin_amdgcn_mfma_f32_16x16x32_bf16(vf[kc][dt], pb[kc], o[set][dt], 0, 0, 0);
      }
    }
    __syncthreads();  // drains vmcnt (next tile staged) + all waves done with cur
    cur ^= 1;
  }

  // epilogue: o[set][dt][j] = O[q=qlo+ql][d=dt*16+sub*4+j]
#pragma unroll
  for (int set = 0; set < 2; ++set) {
    const float inv = 1.0f / l_s[set];
    bf16* yp = y + (size_t)(b * NT + q0 + wid * 32 + set * 16 + ql) * NE + h * 64 + sub * 4;
#pragma unroll
    for (int dt = 0; dt < 4; ++dt) {
      bf16x4v w;
      w[0] = (bf16)(o[set][dt][0] * inv);
      w[1] = (bf16)(o[set][dt][1] * inv);
      w[2] = (bf16)(o[set][dt][2] * inv);
      w[3] = (bf16)(o[set][dt][3] * inv);
      *(bf16x4v*)(yp + dt * 16) = w;
    }
  }
}

// ---------------------------------------------------------------- launch

extern "C" void kernel_launch(void* const* d_in, const int* in_sizes, int n_in,
                              void* d_out, int out_size, void* d_ws, size_t ws_size,
                              hipStream_t stream) {
  const float* x = (const float*)d_in[0];
  const float* Wq = (const float*)d_in[1];
  const float* Wk = (const float*)d_in[2];
  const float* Wv = (const float*)d_in[3];
  const float* Wo = (const float*)d_in[4];
  float* out = (float*)d_out;

  char* ws = (char*)d_ws;
  size_t off = 0;
  auto alloc = [&](size_t bytes) -> void* {
    void* p = ws + off;
    off += (bytes + 255) & ~(size_t)255;
    return p;
  };
  bf16* xb = (bf16*)alloc((size_t)NBT * NE * 2);
  bf16* wqkv_t = (bf16*)alloc((size_t)NQKV * NE * 2);
  bf16* wo_t = (bf16*)alloc((size_t)NE * NE * 2);
  bf16* qkv = (bf16*)alloc((size_t)NBT * NQKV * 2);
  bf16* vtb = (bf16*)alloc((size_t)NB * NHKV * ND * NT * 2);
  bf16* yb = (bf16*)alloc((size_t)NBT * NE * 2);
  float* tab = (float*)alloc((size_t)NT * 64 * 4);

  cvt_bf16_kernel<<<2048, 256, 0, stream>>>(x, xb, NBT * NE / 4);
  dim3 tb(32, 8);
  transpose_cvt_kernel<<<dim3(64, 64), tb, 0, stream>>>(Wq, wqkv_t, 2048, 0);
  transpose_cvt_kernel<<<dim3(16, 64), tb, 0, stream>>>(Wk, wqkv_t, 512, 2048);
  transpose_cvt_kernel<<<dim3(16, 64), tb, 0, stream>>>(Wv, wqkv_t, 512, 2560);
  transpose_cvt_kernel<<<dim3(64, 64), tb, 0, stream>>>(Wo, wo_t, 2048, 0);
  rope_table_kernel<<<(NT * 32 + 255) / 256, 256, 0, stream>>>(tab);

  gemm_bt_kernel<bf16><<<dim3(NQKV / 128, NBT / 128), 256, 0, stream>>>(
      xb, wqkv_t, qkv, NBT, NQKV, NE);
  rope_apply_kernel<<<(NBT * 1280 + 255) / 256, 256, 0, stream>>>(qkv, tab);
  build_vt_kernel<<<dim3(2, 64, 16), tb, 0, stream>>>(qkv, vtb);
  attn_kernel<<<dim3(NT / 128, NB * NH), 256, 0, stream>>>(qkv, vtb, yb);
  gemm_bt_kernel<float><<<dim3(NE / 128, NBT / 128), 256, 0, stream>>>(
      yb, wo_t, out, NBT, NE, NE);
}

// Round 3
// 249.589 us; speedup vs baseline: 1.4952x; 1.2210x over previous
//
#include <hip/hip_runtime.h>
#include <hip/hip_bf16.h>
#include <cstdint>
#include <cstddef>

typedef __bf16 bf16;
typedef __attribute__((ext_vector_type(8))) __bf16 bf16x8;
typedef __attribute__((ext_vector_type(4))) __bf16 bf16x4v;
typedef __attribute__((ext_vector_type(4))) float f32x4;

#define NB 2
#define NT 2048
#define NE 2048
#define NH 32
#define NHKV 8
#define ND 64
#define NBT (NB * NT)
#define NQKV 3072

__device__ __forceinline__ void gload_lds16(const void* g, void* l) {
  __builtin_amdgcn_global_load_lds(
      (const __attribute__((address_space(1))) unsigned int*)g,
      (__attribute__((address_space(3))) unsigned int*)l, 16, 0, 0);
}

// XOR swizzle for 128-byte LDS rows: spreads the 16-way bank conflict.
__device__ __forceinline__ int swz(int row, int byteoff) {
  return (row * 128 + byteoff) ^ ((row & 7) << 4);
}

// ---------------------------------------------------------------- pack kernels

__global__ void cvt_bf16_kernel(const float* __restrict__ in, bf16* __restrict__ out, int n4) {
  int i = blockIdx.x * blockDim.x + threadIdx.x;
  const int stride = gridDim.x * blockDim.x;
  for (; i < n4; i += stride) {
    const float4 v = ((const float4*)in)[i];
    bf16x4v o;
    o[0] = (bf16)v.x; o[1] = (bf16)v.y; o[2] = (bf16)v.z; o[3] = (bf16)v.w;
    ((bf16x4v*)out)[i] = o;
  }
}

// out[rowoff + c][k] = (bf16) in[k][c];  in: [2048][ncols] fp32, out LD = 2048
__global__ void transpose_cvt_kernel(const float* __restrict__ in, bf16* __restrict__ out,
                                     int ncols, int rowoff) {
  __shared__ float tile[32][33];
  const int c0 = blockIdx.x * 32;
  const int k0 = blockIdx.y * 32;
  const int tx = threadIdx.x, ty = threadIdx.y;
#pragma unroll
  for (int j = 0; j < 4; ++j)
    tile[ty + j * 8][tx] = in[(size_t)(k0 + ty + j * 8) * ncols + c0 + tx];
  __syncthreads();
#pragma unroll
  for (int j = 0; j < 4; ++j)
    out[(size_t)(rowoff + c0 + ty + j * 8) * 2048 + k0 + tx] = (bf16)tile[tx][ty + j * 8];
}

__global__ void rope_table_kernel(float* __restrict__ tab) {
  int i = blockIdx.x * 256 + threadIdx.x;
  if (i >= NT * 32) return;
  const int t = i >> 5, d = i & 31;
  const float inv = expf(-(float)d * 0.28782313662425574f);  // ln(10000)/32
  const float ang = (float)t * inv;
  tab[t * 64 + d] = cosf(ang);
  tab[t * 64 + 32 + d] = sinf(ang);
}

// vt[b][hk][d][t] = qkv[b*T+t][2560 + hk*64 + d]
__global__ void build_vt_kernel(const bf16* __restrict__ qkv, bf16* __restrict__ vt) {
  __shared__ bf16 tile[32][33];
  const int bhk = blockIdx.z;
  const int b = bhk >> 3, hk = bhk & 7;
  const int d0 = blockIdx.x * 32, t0 = blockIdx.y * 32;
  const int tx = threadIdx.x, ty = threadIdx.y;
#pragma unroll
  for (int j = 0; j < 4; ++j)
    tile[ty + j * 8][tx] = qkv[(size_t)(b * NT + t0 + ty + j * 8) * NQKV + 2560 + hk * 64 + d0 + tx];
  __syncthreads();
#pragma unroll
  for (int j = 0; j < 4; ++j)
    vt[((size_t)(b * NHKV + hk) * 64 + d0 + ty + j * 8) * NT + t0 + tx] = tile[tx][ty + j * 8];
}

// ---------------------------------------------------------------- GEMM (B^T)
// C[M][N] = A[M][K] * Bt[N][K]^T ; 128x128 tile, BK=32, 4 waves.
// ROPE: rotate (d, d+32) pairs of q/k heads in the epilogue (cols < 2560).

template <typename CT, bool ROPE>
__global__ __launch_bounds__(256)
void gemm_bt_kernel(const bf16* __restrict__ A, const bf16* __restrict__ Bt,
                    CT* __restrict__ C, int M, int N, int K,
                    const float* __restrict__ tab) {
  __shared__ __align__(16) bf16 As[128 * 32];
  __shared__ __align__(16) bf16 Bs[128 * 32];
  const int tid = threadIdx.x;
  const int lane = tid & 63, wid = tid >> 6;
  const int wr = wid >> 1, wc = wid & 1;
  const int m0 = blockIdx.y * 128, n0 = blockIdx.x * 128;
  const int srow = tid >> 2;          // 0..63 staging row
  const int skoff = (tid & 3) * 8;    // staging k offset
  const bf16* ga = A + (size_t)(m0 + srow) * K + skoff;
  const bf16* gb = Bt + (size_t)(n0 + srow) * K + skoff;
  const int fr = lane & 15;
  const int fk = (lane >> 4) * 8;
  f32x4 acc[4][4] = {};

  for (int k0 = 0; k0 < K; k0 += 32) {
    gload_lds16(ga + k0, &As[tid * 8]);
    gload_lds16(ga + k0 + (size_t)64 * K, &As[2048 + tid * 8]);
    gload_lds16(gb + k0, &Bs[tid * 8]);
    gload_lds16(gb + k0 + (size_t)64 * K, &Bs[2048 + tid * 8]);
    __syncthreads();
    bf16x8 af[4], bfr[4];
#pragma unroll
    for (int m = 0; m < 4; ++m)
      af[m] = *(const bf16x8*)&As[(wr * 64 + m * 16 + fr) * 32 + fk];
#pragma unroll
    for (int n = 0; n < 4; ++n)
      bfr[n] = *(const bf16x8*)&Bs[(wc * 64 + n * 16 + fr) * 32 + fk];
#pragma unroll
    for (int m = 0; m < 4; ++m)
#pragma unroll
      for (int n = 0; n < 4; ++n)
        acc[m][n] = __builtin_amdgcn_mfma_f32_16x16x32_bf16(af[m], bfr[n], acc[m][n], 0, 0, 0);
    __syncthreads();
  }

  const int orow0 = m0 + wr * 64 + (lane >> 4) * 4;
  const int ocol0 = n0 + wc * 64 + fr;
  const bool do_rope = ROPE && (n0 + wc * 64) < 2560;
#pragma unroll
  for (int m = 0; m < 4; ++m) {
#pragma unroll
    for (int j = 0; j < 4; ++j) {
      const int row = orow0 + m * 16 + j;
      float v0 = acc[m][0][j], v1 = acc[m][1][j], v2 = acc[m][2][j], v3 = acc[m][3][j];
      if (do_rope) {
        const int t = row & (NT - 1);
        const float c0 = tab[t * 64 + fr],      s0 = tab[t * 64 + 32 + fr];
        const float c1 = tab[t * 64 + 16 + fr], s1 = tab[t * 64 + 48 + fr];
        const float a0 = v0, a2 = v2;
        v0 = a0 * c0 - a2 * s0;
        v2 = a2 * c0 + a0 * s0;
        const float a1 = v1, a3 = v3;
        v1 = a1 * c1 - a3 * s1;
        v3 = a3 * c1 + a1 * s1;
      }
      CT* cp = &C[(size_t)row * N + ocol0];
      cp[0] = (CT)v0; cp[16] = (CT)v1; cp[32] = (CT)v2; cp[48] = (CT)v3;
    }
  }
}

// ---------------------------------------------------------------- attention
// Swapped-operand flash attention. One block = 128 q rows of one (b,h).
// 4 waves x 32 q rows (2 sets of 16). KVBLK = 64, causal.
// Grid is 1-D global big-first (uniform per-CU work; same-bh blocks land on
// the same XCD). K is stored row-PERMUTED in LDS (source-permuted
// global_load_lds, linear dest) so kf reads are bank-conflict-free.
// Softmax in log2 domain with defer-max (T13); setprio around MFMA (T5).

__global__ __launch_bounds__(256)
void attn_kernel(const bf16* __restrict__ qkv, const bf16* __restrict__ vt,
                 bf16* __restrict__ y) {
  const int bid = blockIdx.x;
  const int qtb = 15 - (bid >> 6);   // big blocks dispatched first
  const int bh = bid & 63;
  const int b = bh >> 5, h = bh & 31, hk = h >> 2;
  const int q0 = qtb * 128;

  __shared__ __align__(16) bf16 Kb0[4096], Kb1[4096], Vb0[4096], Vb1[4096];

  const int tid = threadIdx.x;
  const int lane = tid & 63, wid = tid >> 6;
  const int ql = lane & 15;
  const int sub = lane >> 4;

  // staging: dest linear row st_r / st_r+32, chunk tid&7; source column chunk
  // pre-swizzled by dest row (rule #21); K source ROW permuted so that LDS
  // row u holds kv 32(n>>1)+4(n&1)+8(t>>2)+(t&3), n=u>>4, t=u&15.
  const int st_r = tid >> 3;
  const int kperm = 4 * (st_r >> 4) + 8 * ((st_r >> 2) & 3) + (st_r & 3);
  const int csw = ((tid & 7) ^ (st_r & 7)) * 8;
  const bf16* kgbase = qkv + (size_t)(b * NT + kperm) * NQKV + 2048 + hk * 64 + csw;
  const bf16* vgbase = vt + ((size_t)(b * NHKV + hk) * 64 + st_r) * NT + csw;

  auto STAGE = [&](bf16* Kd, bf16* Vd, int kv0) {
    const bf16* kg = kgbase + (size_t)kv0 * NQKV;
    gload_lds16(kg, Kd + tid * 8);
    gload_lds16(kg + (size_t)32 * NQKV, Kd + 2048 + tid * 8);
    const bf16* vg = vgbase + kv0;
    gload_lds16(vg, Vd + tid * 8);
    gload_lds16(vg + 32 * NT, Vd + 2048 + tid * 8);
  };

  // Q fragments (post-RoPE): B-operand, col=q=ql, k=d=sub*8+j (+32c)
  bf16x8 qf[2][2];
#pragma unroll
  for (int set = 0; set < 2; ++set) {
    const bf16* qp = qkv + (size_t)(b * NT + q0 + wid * 32 + set * 16 + ql) * NQKV + h * 64 + sub * 8;
    qf[set][0] = *(const bf16x8*)qp;
    qf[set][1] = *(const bf16x8*)(qp + 32);
  }

  f32x4 o[2][4] = {};
  float m_s[2] = {-1e30f, -1e30f};
  float l_s[2] = {0.f, 0.f};
  const float C = 0.18033688011112042f;  // 0.125 * log2(e)

  const int ntiles = 2 * qtb + 2;
  STAGE(Kb0, Vb0, 0);
  __syncthreads();

  int cur = 0;
  for (int it = 0; it < ntiles; ++it) {
    const int kv0 = it * 64;
    bf16* Ksb = cur ? Kb1 : Kb0;
    bf16* Vsb = cur ? Vb1 : Vb0;
    if (it + 1 < ntiles) STAGE(cur ? Kb0 : Kb1, cur ? Vb0 : Vb1, kv0 + 64);

    if (kv0 <= q0 + wid * 32 + 47) {  // at least one set active for this wave
      // K fragments: LDS rows are pre-permuted -> linear row n*16+ql read,
      // XOR spans all 8 slots (2-way, free).
      bf16x8 kf[4][2];
#pragma unroll
      for (int n = 0; n < 4; ++n)
#pragma unroll
        for (int c = 0; c < 2; ++c)
          kf[n][c] = *(const bf16x8*)((const char*)Ksb + swz(n * 16 + ql, c * 64 + sub * 16));
      // V^T fragments: A-operand, row=d=dt*16+ql, k=kv=kc*32+sub*8+j
      bf16x8 vf[2][4];
#pragma unroll
      for (int kc = 0; kc < 2; ++kc)
#pragma unroll
        for (int dt = 0; dt < 4; ++dt)
          vf[kc][dt] = *(const bf16x8*)((const char*)Vsb + swz(dt * 16 + ql, kc * 64 + sub * 16));

#pragma unroll
      for (int set = 0; set < 2; ++set) {
        const int qlo = q0 + wid * 32 + set * 16;
        if (kv0 > qlo + 15) continue;  // fully masked for this set

        f32x4 s[4] = {};
        __builtin_amdgcn_s_setprio(1);
#pragma unroll
        for (int n = 0; n < 4; ++n) {
          s[n] = __builtin_amdgcn_mfma_f32_16x16x32_bf16(kf[n][0], qf[set][0], s[n], 0, 0, 0);
          s[n] = __builtin_amdgcn_mfma_f32_16x16x32_bf16(kf[n][1], qf[set][1], s[n], 0, 0, 0);
        }
        __builtin_amdgcn_s_setprio(0);

        // lane holds S^T[kv = kv0+32(n>>1)+4(n&1)+8sub+j][q = qlo+ql]
        float p[4][4];
        if (kv0 + 63 > qlo) {
          const int qrow = qlo + ql;
#pragma unroll
          for (int n = 0; n < 4; ++n) {
            const int kvb = kv0 + 32 * (n >> 1) + 4 * (n & 1) + 8 * sub;
#pragma unroll
            for (int j = 0; j < 4; ++j) {
              float v = s[n][j] * C;
              if (kvb + j > qrow) v = -1e30f;
              p[n][j] = v;
            }
          }
        } else {
#pragma unroll
          for (int n = 0; n < 4; ++n)
#pragma unroll
            for (int j = 0; j < 4; ++j)
              p[n][j] = s[n][j] * C;
        }

        // in-register online softmax, log2 domain (column q lives in lanes
        // ql+{0,16,32,48})
        float rmax = p[0][0];
#pragma unroll
        for (int n = 0; n < 4; ++n)
#pragma unroll
          for (int j = 0; j < 4; ++j) rmax = fmaxf(rmax, p[n][j]);
        rmax = fmaxf(rmax, __shfl_xor(rmax, 16));
        rmax = fmaxf(rmax, __shfl_xor(rmax, 32));

        // defer-max (T13): only rescale when the max grew by > 8 (log2)
        if (!__all(rmax <= m_s[set] + 8.0f)) {
          const float mnew = fmaxf(m_s[set], rmax);
          const float sc = exp2f(m_s[set] - mnew);
          m_s[set] = mnew;
          l_s[set] *= sc;
#pragma unroll
          for (int dt = 0; dt < 4; ++dt) o[set][dt] *= sc;
        }
        const float mcur = m_s[set];

        float rsum = 0.f;
        bf16x8 pb[2];  // [kc]: elements 0-3 from tile 2kc, 4-7 from tile 2kc+1
#pragma unroll
        for (int n = 0; n < 4; ++n)
#pragma unroll
          for (int j = 0; j < 4; ++j) {
            const float e = exp2f(p[n][j] - mcur);
            rsum += e;
            pb[n >> 1][(n & 1) * 4 + j] = (bf16)e;
          }
        rsum += __shfl_xor(rsum, 16);
        rsum += __shfl_xor(rsum, 32);
        l_s[set] += rsum;

        // O^T[d][q] += V^T[d][kv] * P^T[kv][q]  (full-rate x32, P in-register)
        __builtin_amdgcn_s_setprio(1);
#pragma unroll
        for (int kc = 0; kc < 2; ++kc)
#pragma unroll
          for (int dt = 0; dt < 4; ++dt)
            o[set][dt] = __builtin_amdgcn_mfma_f32_16x16x32_bf16(vf[kc][dt], pb[kc], o[set][dt], 0, 0, 0);
        __builtin_amdgcn_s_setprio(0);
      }
    }
    __syncthreads();  // drains vmcnt (next tile staged) + all waves done with cur
    cur ^= 1;
  }

  // epilogue: o[set][dt][j] = O[q=qlo+ql][d=dt*16+sub*4+j]
#pragma unroll
  for (int set = 0; set < 2; ++set) {
    const float inv = 1.0f / l_s[set];
    bf16* yp = y + (size_t)(b * NT + q0 + wid * 32 + set * 16 + ql) * NE + h * 64 + sub * 4;
#pragma unroll
    for (int dt = 0; dt < 4; ++dt) {
      bf16x4v w;
      w[0] = (bf16)(o[set][dt][0] * inv);
      w[1] = (bf16)(o[set][dt][1] * inv);
      w[2] = (bf16)(o[set][dt][2] * inv);
      w[3] = (bf16)(o[set][dt][3] * inv);
      *(bf16x4v*)(yp + dt * 16) = w;
    }
  }
}

// ---------------------------------------------------------------- launch

extern "C" void kernel_launch(void* const* d_in, const int* in_sizes, int n_in,
                              void* d_out, int out_size, void* d_ws, size_t ws_size,
                              hipStream_t stream) {
  const float* x = (const float*)d_in[0];
  const float* Wq = (const float*)d_in[1];
  const float* Wk = (const float*)d_in[2];
  const float* Wv = (const float*)d_in[3];
  const float* Wo = (const float*)d_in[4];
  float* out = (float*)d_out;

  char* ws = (char*)d_ws;
  size_t off = 0;
  auto alloc = [&](size_t bytes) -> void* {
    void* p = ws + off;
    off += (bytes + 255) & ~(size_t)255;
    return p;
  };
  bf16* xb = (bf16*)alloc((size_t)NBT * NE * 2);
  bf16* wqkv_t = (bf16*)alloc((size_t)NQKV * NE * 2);
  bf16* wo_t = (bf16*)alloc((size_t)NE * NE * 2);
  bf16* qkv = (bf16*)alloc((size_t)NBT * NQKV * 2);
  bf16* vtb = (bf16*)alloc((size_t)NB * NHKV * ND * NT * 2);
  bf16* yb = (bf16*)alloc((size_t)NBT * NE * 2);
  float* tab = (float*)alloc((size_t)NT * 64 * 4);

  cvt_bf16_kernel<<<2048, 256, 0, stream>>>(x, xb, NBT * NE / 4);
  dim3 tb(32, 8);
  transpose_cvt_kernel<<<dim3(64, 64), tb, 0, stream>>>(Wq, wqkv_t, 2048, 0);
  transpose_cvt_kernel<<<dim3(16, 64), tb, 0, stream>>>(Wk, wqkv_t, 512, 2048);
  transpose_cvt_kernel<<<dim3(16, 64), tb, 0, stream>>>(Wv, wqkv_t, 512, 2560);
  transpose_cvt_kernel<<<dim3(64, 64), tb, 0, stream>>>(Wo, wo_t, 2048, 0);
  rope_table_kernel<<<(NT * 32 + 255) / 256, 256, 0, stream>>>(tab);

  gemm_bt_kernel<bf16, true><<<dim3(NQKV / 128, NBT / 128), 256, 0, stream>>>(
      xb, wqkv_t, qkv, NBT, NQKV, NE, tab);
  build_vt_kernel<<<dim3(2, 64, 16), tb, 0, stream>>>(qkv, vtb);
  attn_kernel<<<dim3(NT / 128 * 64), 256, 0, stream>>>(qkv, vtb, yb);
  gemm_bt_kernel<float, false><<<dim3(NE / 128, NBT / 128), 256, 0, stream>>>(
      yb, wo_t, out, NBT, NE, NE, nullptr);
}

// Round 4
// 249.259 us; speedup vs baseline: 1.4972x; 1.0013x over previous
//
#include <hip/hip_runtime.h>
#include <hip/hip_bf16.h>
#include <cstdint>
#include <cstddef>

typedef __bf16 bf16;
typedef __attribute__((ext_vector_type(8))) __bf16 bf16x8;
typedef __attribute__((ext_vector_type(4))) __bf16 bf16x4v;
typedef __attribute__((ext_vector_type(4))) float f32x4;

#define NB 2
#define NT 2048
#define NE 2048
#define NH 32
#define NHKV 8
#define ND 64
#define NBT (NB * NT)
#define NQKV 3072

__device__ __forceinline__ void gload_lds16(const void* g, void* l) {
  __builtin_amdgcn_global_load_lds(
      (const __attribute__((address_space(1))) unsigned int*)g,
      (__attribute__((address_space(3))) unsigned int*)l, 16, 0, 0);
}

// XOR swizzle for 128-byte LDS rows: spreads the 16-way bank conflict.
__device__ __forceinline__ int swz(int row, int byteoff) {
  return (row * 128 + byteoff) ^ ((row & 7) << 4);
}

// ---------------------------------------------------------------- pack kernels

__global__ void cvt_bf16_kernel(const float* __restrict__ in, bf16* __restrict__ out, int n4) {
  int i = blockIdx.x * blockDim.x + threadIdx.x;
  const int stride = gridDim.x * blockDim.x;
  for (; i < n4; i += stride) {
    const float4 v = ((const float4*)in)[i];
    bf16x4v o;
    o[0] = (bf16)v.x; o[1] = (bf16)v.y; o[2] = (bf16)v.z; o[3] = (bf16)v.w;
    ((bf16x4v*)out)[i] = o;
  }
}

// out[rowoff + c][k] = (bf16) in[k][c];  in: [2048][ncols] fp32, out LD = 2048
__global__ void transpose_cvt_kernel(const float* __restrict__ in, bf16* __restrict__ out,
                                     int ncols, int rowoff) {
  __shared__ float tile[32][33];
  const int c0 = blockIdx.x * 32;
  const int k0 = blockIdx.y * 32;
  const int tx = threadIdx.x, ty = threadIdx.y;
#pragma unroll
  for (int j = 0; j < 4; ++j)
    tile[ty + j * 8][tx] = in[(size_t)(k0 + ty + j * 8) * ncols + c0 + tx];
  __syncthreads();
#pragma unroll
  for (int j = 0; j < 4; ++j)
    out[(size_t)(rowoff + c0 + ty + j * 8) * 2048 + k0 + tx] = (bf16)tile[tx][ty + j * 8];
}

__global__ void rope_table_kernel(float* __restrict__ tab) {
  int i = blockIdx.x * 256 + threadIdx.x;
  if (i >= NT * 32) return;
  const int t = i >> 5, d = i & 31;
  const float inv = expf(-(float)d * 0.28782313662425574f);  // ln(10000)/32
  const float ang = (float)t * inv;
  tab[t * 64 + d] = cosf(ang);
  tab[t * 64 + 32 + d] = sinf(ang);
}

// vt[b][hk][d][t] = qkv[b*T+t][2560 + hk*64 + d]
__global__ void build_vt_kernel(const bf16* __restrict__ qkv, bf16* __restrict__ vt) {
  __shared__ bf16 tile[32][33];
  const int bhk = blockIdx.z;
  const int b = bhk >> 3, hk = bhk & 7;
  const int d0 = blockIdx.x * 32, t0 = blockIdx.y * 32;
  const int tx = threadIdx.x, ty = threadIdx.y;
#pragma unroll
  for (int j = 0; j < 4; ++j)
    tile[ty + j * 8][tx] = qkv[(size_t)(b * NT + t0 + ty + j * 8) * NQKV + 2560 + hk * 64 + d0 + tx];
  __syncthreads();
#pragma unroll
  for (int j = 0; j < 4; ++j)
    vt[((size_t)(b * NHKV + hk) * 64 + d0 + ty + j * 8) * NT + t0 + tx] = tile[tx][ty + j * 8];
}

// ---------------------------------------------------------------- GEMM (8-phase style)
// C[M][N] = A[M][K] * Bt[N][K]^T.  BM=256, BN=128, BK=64, 512 thr / 8 waves
// (4M x 2N), per-wave 64x64. 2 phases per K-tile (phase = K-half of 32),
// double-buffered K-halves, counted vmcnt(3) (never 0 in steady state),
// T2 source-side swizzle (16B-slot XOR within 64B store rows), T5 setprio.
// K-half LDS layout: store-row u = r>>1 (r = tile row), byte =
//   u*128 + (r&1)*64 + (kb ^ ((u&3)<<4)),  kb = K-byte within half (0..63).
// Staged via lane-linear global_load_lds with pre-swizzled global source.

template <typename CT, bool ROPE>
__global__ __launch_bounds__(512, 2)
void gemm8p_kernel(const bf16* __restrict__ A, const bf16* __restrict__ Bt,
                   CT* __restrict__ C, int M, int N, int K,
                   const float* __restrict__ tab) {
  __shared__ __align__(16) bf16 LA[2][2][8192];
  __shared__ __align__(16) bf16 LB[2][2][4096];
  const int tid = threadIdx.x, lane = tid & 63, w = tid >> 6;
  const int wm = w >> 1, wn = w & 1;
  const int gx = N >> 7;
  const int cpx = (int)gridDim.x >> 3;
  const int swzb = ((int)blockIdx.x & 7) * cpx + ((int)blockIdx.x >> 3);
  const int bx = swzb % gx, by = swzb / gx;
  const int m0 = by * 256, n0 = bx * 128;

  // staging source (per lane): row + swizzled k-offset
  const int srow = w * 16 + 2 * (lane >> 3) + ((lane >> 2) & 1);
  const int ke = 8 * ((lane & 3) ^ ((lane >> 3) & 3));
  const bf16* gA = A + (size_t)(m0 + srow) * K + ke;
  const bf16* gB = Bt + (size_t)(n0 + srow) * K + ke;
  const size_t rowK128 = (size_t)128 * K;
  const int NTK = K >> 6;

  // frag read offsets (elements):
  //   elem = (base32 + f*8 + (fr>>1))*64 + (fr&1)*32 + 8*(fq ^ ((fr>>1)&3))
  const int fr = lane & 15, fq = lane >> 4;
  const int fcol = (fr & 1) * 32 + 8 * (fq ^ ((fr >> 1) & 3));
  const int abase = (wm * 32 + (fr >> 1)) * 64 + fcol;
  const int bbase = (wn * 32 + (fr >> 1)) * 64 + fcol;

  f32x4 acc[4][4] = {};

#define STAGE_G(buf, ks, kg)                                                      \
  do {                                                                            \
    gload_lds16(gA + (kg) + (ks) * 32, &LA[buf][ks][tid * 8]);                    \
    gload_lds16(gA + (kg) + (ks) * 32 + rowK128, &LA[buf][ks][4096 + tid * 8]);   \
    gload_lds16(gB + (kg) + (ks) * 32, &LB[buf][ks][tid * 8]);                    \
  } while (0)

  STAGE_G(0, 0, 0);
  STAGE_G(0, 1, 0);
  asm volatile("s_waitcnt vmcnt(3)" ::: "memory");
  __builtin_amdgcn_s_barrier();

  for (int t = 0; t < NTK; ++t) {
    const int buf = t & 1;
    const bool pre = (t + 1 < NTK);
#pragma unroll
    for (int ph = 0; ph < 2; ++ph) {
      bf16x8 af[4], bq[4];
#pragma unroll
      for (int f = 0; f < 4; ++f) {
        af[f] = *(const bf16x8*)&LA[buf][ph][abase + f * 512];
        bq[f] = *(const bf16x8*)&LB[buf][ph][bbase + f * 512];
      }
      if (pre) {
        if (ph == 0) STAGE_G(buf ^ 1, 0, (t + 1) * 64);
        else         STAGE_G(buf ^ 1, 1, (t + 1) * 64);
      }
      __builtin_amdgcn_s_barrier();
      asm volatile("s_waitcnt lgkmcnt(0)" ::: "memory");
      __builtin_amdgcn_sched_barrier(0);
      __builtin_amdgcn_s_setprio(1);
#pragma unroll
      for (int i = 0; i < 4; ++i)
#pragma unroll
        for (int j = 0; j < 4; ++j)
          acc[i][j] = __builtin_amdgcn_mfma_f32_16x16x32_bf16(af[i], bq[j], acc[i][j], 0, 0, 0);
      __builtin_amdgcn_s_setprio(0);
      if (ph == 0) {
        if (pre) asm volatile("s_waitcnt vmcnt(3)" ::: "memory");
        else     asm volatile("s_waitcnt vmcnt(0)" ::: "memory");
      } else if (pre) {
        asm volatile("s_waitcnt vmcnt(3)" ::: "memory");
      }
      __builtin_amdgcn_s_barrier();
    }
  }
#undef STAGE_G

  const bool do_rope = ROPE && (n0 + wn * 64) < 2560;
#pragma unroll
  for (int i = 0; i < 4; ++i) {
#pragma unroll
    for (int jj = 0; jj < 4; ++jj) {
      const int row = m0 + wm * 64 + i * 16 + fq * 4 + jj;
      float v0 = acc[i][0][jj], v1 = acc[i][1][jj], v2 = acc[i][2][jj], v3 = acc[i][3][jj];
      if (do_rope) {
        const int tt = row & (NT - 1);
        const float c0 = tab[tt * 64 + fr],      s0 = tab[tt * 64 + 32 + fr];
        const float c1 = tab[tt * 64 + 16 + fr], s1 = tab[tt * 64 + 48 + fr];
        const float a0 = v0, a2 = v2;
        v0 = a0 * c0 - a2 * s0;
        v2 = a2 * c0 + a0 * s0;
        const float a1 = v1, a3 = v3;
        v1 = a1 * c1 - a3 * s1;
        v3 = a3 * c1 + a1 * s1;
      }
      CT* cp = &C[(size_t)row * N + n0 + wn * 64 + fr];
      cp[0] = (CT)v0; cp[16] = (CT)v1; cp[32] = (CT)v2; cp[48] = (CT)v3;
    }
  }
}

// ---------------------------------------------------------------- attention
// Swapped-operand flash attention. One block = 128 q rows of one (b,h).
// 4 waves x 32 q rows (2 sets of 16). KVBLK = 64, causal.
// Grid is 1-D global big-first (uniform per-CU work; same-bh blocks land on
// the same XCD). K is stored row-PERMUTED in LDS (source-permuted
// global_load_lds, linear dest) so kf reads are bank-conflict-free.
// Softmax in log2 domain with defer-max (T13); setprio around MFMA (T5).

__global__ __launch_bounds__(256)
void attn_kernel(const bf16* __restrict__ qkv, const bf16* __restrict__ vt,
                 bf16* __restrict__ y) {
  const int bid = blockIdx.x;
  const int qtb = 15 - (bid >> 6);   // big blocks dispatched first
  const int bh = bid & 63;
  const int b = bh >> 5, h = bh & 31, hk = h >> 2;
  const int q0 = qtb * 128;

  __shared__ __align__(16) bf16 Kb0[4096], Kb1[4096], Vb0[4096], Vb1[4096];

  const int tid = threadIdx.x;
  const int lane = tid & 63, wid = tid >> 6;
  const int ql = lane & 15;
  const int sub = lane >> 4;

  // staging: dest linear row st_r / st_r+32, chunk tid&7; source column chunk
  // pre-swizzled by dest row (rule #21); K source ROW permuted so that LDS
  // row u holds kv 32(n>>1)+4(n&1)+8(t>>2)+(t&3), n=u>>4, t=u&15.
  const int st_r = tid >> 3;
  const int kperm = 4 * (st_r >> 4) + 8 * ((st_r >> 2) & 3) + (st_r & 3);
  const int csw = ((tid & 7) ^ (st_r & 7)) * 8;
  const bf16* kgbase = qkv + (size_t)(b * NT + kperm) * NQKV + 2048 + hk * 64 + csw;
  const bf16* vgbase = vt + ((size_t)(b * NHKV + hk) * 64 + st_r) * NT + csw;

  auto STAGE = [&](bf16* Kd, bf16* Vd, int kv0) {
    const bf16* kg = kgbase + (size_t)kv0 * NQKV;
    gload_lds16(kg, Kd + tid * 8);
    gload_lds16(kg + (size_t)32 * NQKV, Kd + 2048 + tid * 8);
    const bf16* vg = vgbase + kv0;
    gload_lds16(vg, Vd + tid * 8);
    gload_lds16(vg + 32 * NT, Vd + 2048 + tid * 8);
  };

  // Q fragments (post-RoPE): B-operand, col=q=ql, k=d=sub*8+j (+32c)
  bf16x8 qf[2][2];
#pragma unroll
  for (int set = 0; set < 2; ++set) {
    const bf16* qp = qkv + (size_t)(b * NT + q0 + wid * 32 + set * 16 + ql) * NQKV + h * 64 + sub * 8;
    qf[set][0] = *(const bf16x8*)qp;
    qf[set][1] = *(const bf16x8*)(qp + 32);
  }

  f32x4 o[2][4] = {};
  float m_s[2] = {-1e30f, -1e30f};
  float l_s[2] = {0.f, 0.f};
  const float C = 0.18033688011112042f;  // 0.125 * log2(e)

  const int ntiles = 2 * qtb + 2;
  STAGE(Kb0, Vb0, 0);
  __syncthreads();

  int cur = 0;
  for (int it = 0; it < ntiles; ++it) {
    const int kv0 = it * 64;
    bf16* Ksb = cur ? Kb1 : Kb0;
    bf16* Vsb = cur ? Vb1 : Vb0;
    if (it + 1 < ntiles) STAGE(cur ? Kb0 : Kb1, cur ? Vb0 : Vb1, kv0 + 64);

    if (kv0 <= q0 + wid * 32 + 47) {  // at least one set active for this wave
      // K fragments: LDS rows are pre-permuted -> linear row n*16+ql read,
      // XOR spans all 8 slots (2-way, free).
      bf16x8 kf[4][2];
#pragma unroll
      for (int n = 0; n < 4; ++n)
#pragma unroll
        for (int c = 0; c < 2; ++c)
          kf[n][c] = *(const bf16x8*)((const char*)Ksb + swz(n * 16 + ql, c * 64 + sub * 16));
      // V^T fragments: A-operand, row=d=dt*16+ql, k=kv=kc*32+sub*8+j
      bf16x8 vf[2][4];
#pragma unroll
      for (int kc = 0; kc < 2; ++kc)
#pragma unroll
        for (int dt = 0; dt < 4; ++dt)
          vf[kc][dt] = *(const bf16x8*)((const char*)Vsb + swz(dt * 16 + ql, kc * 64 + sub * 16));

#pragma unroll
      for (int set = 0; set < 2; ++set) {
        const int qlo = q0 + wid * 32 + set * 16;
        if (kv0 > qlo + 15) continue;  // fully masked for this set

        f32x4 s[4] = {};
        __builtin_amdgcn_s_setprio(1);
#pragma unroll
        for (int n = 0; n < 4; ++n) {
          s[n] = __builtin_amdgcn_mfma_f32_16x16x32_bf16(kf[n][0], qf[set][0], s[n], 0, 0, 0);
          s[n] = __builtin_amdgcn_mfma_f32_16x16x32_bf16(kf[n][1], qf[set][1], s[n], 0, 0, 0);
        }
        __builtin_amdgcn_s_setprio(0);

        // lane holds S^T[kv = kv0+32(n>>1)+4(n&1)+8sub+j][q = qlo+ql]
        float p[4][4];
        if (kv0 + 63 > qlo) {
          const int qrow = qlo + ql;
#pragma unroll
          for (int n = 0; n < 4; ++n) {
            const int kvb = kv0 + 32 * (n >> 1) + 4 * (n & 1) + 8 * sub;
#pragma unroll
            for (int j = 0; j < 4; ++j) {
              float v = s[n][j] * C;
              if (kvb + j > qrow) v = -1e30f;
              p[n][j] = v;
            }
          }
        } else {
#pragma unroll
          for (int n = 0; n < 4; ++n)
#pragma unroll
            for (int j = 0; j < 4; ++j)
              p[n][j] = s[n][j] * C;
        }

        // in-register online softmax, log2 domain (column q lives in lanes
        // ql+{0,16,32,48})
        float rmax = p[0][0];
#pragma unroll
        for (int n = 0; n < 4; ++n)
#pragma unroll
          for (int j = 0; j < 4; ++j) rmax = fmaxf(rmax, p[n][j]);
        rmax = fmaxf(rmax, __shfl_xor(rmax, 16));
        rmax = fmaxf(rmax, __shfl_xor(rmax, 32));

        // defer-max (T13): only rescale when the max grew by > 8 (log2)
        if (!__all(rmax <= m_s[set] + 8.0f)) {
          const float mnew = fmaxf(m_s[set], rmax);
          const float sc = exp2f(m_s[set] - mnew);
          m_s[set] = mnew;
          l_s[set] *= sc;
#pragma unroll
          for (int dt = 0; dt < 4; ++dt) o[set][dt] *= sc;
        }
        const float mcur = m_s[set];

        float rsum = 0.f;
        bf16x8 pb[2];  // [kc]: elements 0-3 from tile 2kc, 4-7 from tile 2kc+1
#pragma unroll
        for (int n = 0; n < 4; ++n)
#pragma unroll
          for (int j = 0; j < 4; ++j) {
            const float e = exp2f(p[n][j] - mcur);
            rsum += e;
            pb[n >> 1][(n & 1) * 4 + j] = (bf16)e;
          }
        rsum += __shfl_xor(rsum, 16);
        rsum += __shfl_xor(rsum, 32);
        l_s[set] += rsum;

        // O^T[d][q] += V^T[d][kv] * P^T[kv][q]  (full-rate x32, P in-register)
        __builtin_amdgcn_s_setprio(1);
#pragma unroll
        for (int kc = 0; kc < 2; ++kc)
#pragma unroll
          for (int dt = 0; dt < 4; ++dt)
            o[set][dt] = __builtin_amdgcn_mfma_f32_16x16x32_bf16(vf[kc][dt], pb[kc], o[set][dt], 0, 0, 0);
        __builtin_amdgcn_s_setprio(0);
      }
    }
    __syncthreads();  // drains vmcnt (next tile staged) + all waves done with cur
    cur ^= 1;
  }

  // epilogue: o[set][dt][j] = O[q=qlo+ql][d=dt*16+sub*4+j]
#pragma unroll
  for (int set = 0; set < 2; ++set) {
    const float inv = 1.0f / l_s[set];
    bf16* yp = y + (size_t)(b * NT + q0 + wid * 32 + set * 16 + ql) * NE + h * 64 + sub * 4;
#pragma unroll
    for (int dt = 0; dt < 4; ++dt) {
      bf16x4v w;
      w[0] = (bf16)(o[set][dt][0] * inv);
      w[1] = (bf16)(o[set][dt][1] * inv);
      w[2] = (bf16)(o[set][dt][2] * inv);
      w[3] = (bf16)(o[set][dt][3] * inv);
      *(bf16x4v*)(yp + dt * 16) = w;
    }
  }
}

// ---------------------------------------------------------------- launch

extern "C" void kernel_launch(void* const* d_in, const int* in_sizes, int n_in,
                              void* d_out, int out_size, void* d_ws, size_t ws_size,
                              hipStream_t stream) {
  const float* x = (const float*)d_in[0];
  const float* Wq = (const float*)d_in[1];
  const float* Wk = (const float*)d_in[2];
  const float* Wv = (const float*)d_in[3];
  const float* Wo = (const float*)d_in[4];
  float* out = (float*)d_out;

  char* ws = (char*)d_ws;
  size_t off = 0;
  auto alloc = [&](size_t bytes) -> void* {
    void* p = ws + off;
    off += (bytes + 255) & ~(size_t)255;
    return p;
  };
  bf16* xb = (bf16*)alloc((size_t)NBT * NE * 2);
  bf16* wqkv_t = (bf16*)alloc((size_t)NQKV * NE * 2);
  bf16* wo_t = (bf16*)alloc((size_t)NE * NE * 2);
  bf16* qkv = (bf16*)alloc((size_t)NBT * NQKV * 2);
  bf16* vtb = (bf16*)alloc((size_t)NB * NHKV * ND * NT * 2);
  bf16* yb = (bf16*)alloc((size_t)NBT * NE * 2);
  float* tab = (float*)alloc((size_t)NT * 64 * 4);

  cvt_bf16_kernel<<<2048, 256, 0, stream>>>(x, xb, NBT * NE / 4);
  dim3 tb(32, 8);
  transpose_cvt_kernel<<<dim3(64, 64), tb, 0, stream>>>(Wq, wqkv_t, 2048, 0);
  transpose_cvt_kernel<<<dim3(16, 64), tb, 0, stream>>>(Wk, wqkv_t, 512, 2048);
  transpose_cvt_kernel<<<dim3(16, 64), tb, 0, stream>>>(Wv, wqkv_t, 512, 2560);
  transpose_cvt_kernel<<<dim3(64, 64), tb, 0, stream>>>(Wo, wo_t, 2048, 0);
  rope_table_kernel<<<(NT * 32 + 255) / 256, 256, 0, stream>>>(tab);

  gemm8p_kernel<bf16, true><<<dim3((NQKV / 128) * (NBT / 256)), 512, 0, stream>>>(
      xb, wqkv_t, qkv, NBT, NQKV, NE, tab);
  build_vt_kernel<<<dim3(2, 64, 16), tb, 0, stream>>>(qkv, vtb);
  attn_kernel<<<dim3(NT / 128 * 64), 256, 0, stream>>>(qkv, vtb, yb);
  gemm8p_kernel<float, false><<<dim3((NE / 128) * (NBT / 256)), 512, 0, stream>>>(
      yb, wo_t, out, NBT, NE, NE, nullptr);
}